// Round 12
// baseline (286.344 us; speedup 1.0000x reference)
//
#include <hip/hip_runtime.h>
#include <hip/hip_bf16.h>
#include <stdint.h>

typedef int   i32x4  __attribute__((ext_vector_type(4)));
typedef int   v8i    __attribute__((ext_vector_type(8)));
typedef float f32x4  __attribute__((ext_vector_type(4)));
typedef float f32x16 __attribute__((ext_vector_type(16)));

#define LOG2E   1.4426950408889634f
#define LN2     0.6931471805599453f
#define C_SCALED 86.56170245f   // 60*log2(e); carried in MFMA C-operand, cancels in final
#define SCALE1  0x7F7F7F7F      // e8m0 1.0 -> unit MX scales

__device__ __forceinline__ void gload_lds16(const void* gsrc, void* ldst) {
    __builtin_amdgcn_global_load_lds(
        (const __attribute__((address_space(1))) unsigned int*)gsrc,
        (__attribute__((address_space(3))) unsigned int*)ldst,
        16, 0, 0);
}

// ---------------- kernel 1: permute + fp32 -> fp8 e4m3 ----------------
// pred[b][n][c][h][w] -> A[m][c] fp8 row-major, scaled by log2(e). gt -> B[m][c] fp8.
// Also zeroes the reduce done-counter (graph-replay-safe: runs first every call).
__global__ void convert_perm(const float* __restrict__ pred, const float* __restrict__ gt,
                             unsigned char* __restrict__ Ab, unsigned char* __restrict__ Bb,
                             unsigned int* __restrict__ counter)
{
    if (blockIdx.x == 0 && threadIdx.x == 0) *counter = 0u;
    const int slab = blockIdx.x & 511;
    const bool isA = blockIdx.x < 512;
    const float scale = isA ? LOG2E : 1.0f;
    const float* src = (isA ? pred : gt) + (size_t)slab * 4096;   // [256 c][16 hw]
    unsigned char* dst = (isA ? Ab : Bb) + (size_t)slab * 4096;   // [16 hw][256 c]
    const int t  = threadIdx.x;
    const int hw = t >> 4;
    const int c0 = (t & 15) * 16;
    int d[4];
    #pragma unroll
    for (int q = 0; q < 4; ++q) {
        const float v0 = src[(c0 + q * 4 + 0) * 16 + hw] * scale;
        const float v1 = src[(c0 + q * 4 + 1) * 16 + hw] * scale;
        const float v2 = src[(c0 + q * 4 + 2) * 16 + hw] * scale;
        const float v3 = src[(c0 + q * 4 + 3) * 16 + hw] * scale;
        int r = __builtin_amdgcn_cvt_pk_fp8_f32(v0, v1, 0, false);
        r     = __builtin_amdgcn_cvt_pk_fp8_f32(v2, v3, r, true);
        d[q] = r;
    }
    *(i32x4*)(dst + hw * 256 + c0) = (i32x4){d[0], d[1], d[2], d[3]};
}

// ---------------- kernel 2: fused MX-fp8 GEMM + exp2-sum + diag ----------------
// 4-wave blocks (256 thr), tile 256i x 512j, A in regs (pfr 2x4 v8i = 64 VGPR),
// B dbuf in LDS (2x32KB) -> 2 blocks/CU. 4 steps of 128j: ONE vmcnt(0)+barrier
// per step (32 MFMA). Each half-step: {READB g0 ∥ 4 stage ∥ READB g1 ->
// 16 contiguous MFMA (4 indep acc chains) -> 4 EPJ (trans pipe, overlaps the
// SIMD-mate's MFMA burst)}.
__global__ __launch_bounds__(256) __attribute__((amdgpu_waves_per_eu(2, 2)))
void gemm_lse(const unsigned char* __restrict__ Ab, const unsigned char* __restrict__ Bb,
              float* __restrict__ rowsum_part, float* __restrict__ diagy)
{
    __shared__ __align__(16) char lds[65536];   // two 32KB B buffers
    const int tid  = threadIdx.x;
    const int lane = tid & 63;
    const int w    = tid >> 6;       // 0..3 (i split: 64 rows each)
    const int l31  = lane & 31;
    const int hi   = lane >> 5;

    const int jc = blockIdx.x & 15;  // same-jc blocks 16 apart -> same XCD (L2-local B)
    const int ib = blockIdx.x >> 4;  // 32 i-blocks of 256
    const int i0 = ib << 8;
    const int j0 = jc << 9;

    // ---- A fragments: 64 i-rows/wave -> 2 ifrag x 4 ks, v8i (32B = K 64) each ----
    v8i pfr[2][4];
    {
        const unsigned char* base = Ab + (size_t)(i0 + w * 64 + l31) * 256 + hi * 32;
        #pragma unroll
        for (int f = 0; f < 2; ++f)
            #pragma unroll
            for (int ks = 0; ks < 4; ++ks)
                pfr[f][ks] = *(const v8i*)(base + f * 32 * 256 + ks * 64);
    }

    const unsigned char* Bbase = Bb + (size_t)j0 * 256;
    const int ibase = i0 + w * 64;

// stage 4 x 16B (slots BASE..BASE+3 of 8) into next buffer, inverse-swizzled src
#define STG4(BASE) if (js < 3) { \
    _Pragma("unroll") \
    for (int it_ = 0; it_ < 4; ++it_) { \
        const int ob_ = ((BASE) + it_) * 4096 + tid * 16; \
        const int sb_ = ob_ ^ (((ob_ >> 8) & 15) << 4); \
        gload_lds16(nsrc + sb_, nbuf + ob_); \
    } }

    // prologue: stage step 0 (32KB = 8 x 16B per thread) into buffer 0
    #pragma unroll
    for (int it = 0; it < 8; ++it) {
        const int ob = it * 4096 + tid * 16;
        const int sb = ob ^ (((ob >> 8) & 15) << 4);
        gload_lds16(Bbase + sb, lds + ob);
    }

    float rs[2] = {0.f, 0.f};

// read B j-frag JF (0..3 within step; 4 ks x v8i), XOR-swizzled
#define READB(G, JF) { \
    const int  row_ = (JF) * 32 + l31; \
    const char* rp_ = bufp + row_ * 256; \
    const int  sx_  = (row_ & 15) << 4; \
    _Pragma("unroll") \
    for (int ks_ = 0; ks_ < 4; ++ks_) { \
        const int ko_ = ks_ * 64 + hi * 32; \
        const i32x4 lo_ = *(const i32x4*)(rp_ + ((ko_     ) ^ sx_)); \
        const i32x4 h_  = *(const i32x4*)(rp_ + ((ko_ + 16) ^ sx_)); \
        G[ks_] = (v8i){lo_[0], lo_[1], lo_[2], lo_[3], h_[0], h_[1], h_[2], h_[3]}; \
    } }

// 8-MFMA chain pair: j-frag G x both i-frags, K=256 via 4 chained ks
#define MMJ(G, A0, A1) { \
    _Pragma("unroll") \
    for (int ks_ = 0; ks_ < 4; ++ks_) { \
        A0 = __builtin_amdgcn_mfma_scale_f32_32x32x64_f8f6f4( \
            G[ks_], pfr[0][ks_], A0, 0, 0, 0, SCALE1, 0, SCALE1); \
        A1 = __builtin_amdgcn_mfma_scale_f32_32x32x64_f8f6f4( \
            G[ks_], pfr[1][ks_], A1, 0, 0, 0, SCALE1, 0, SCALE1); \
    } }

#define ZA16(X) { _Pragma("unroll") for (int r_ = 0; r_ < 16; ++r_) X[r_] = -C_SCALED; }

// epilogue for one 32x32 tile: 16 exp2 (tree sum) + diagonal capture.
// C/D layout: col(i)=lane&31, row(j)=(r&3)+8*(r>>2)+4*(lane>>5)
#define EPJ(ACC, IFR, JF) { \
    const int jb_  = jbase + (JF) * 32; \
    const int ibf_ = ibase + (IFR) * 32; \
    float e_[16]; \
    _Pragma("unroll") for (int r_ = 0; r_ < 16; ++r_) e_[r_] = __builtin_amdgcn_exp2f(ACC[r_]); \
    float s_ = ((e_[0]+e_[1])+(e_[2]+e_[3])) + ((e_[4]+e_[5])+(e_[6]+e_[7])) \
             + ((e_[8]+e_[9])+(e_[10]+e_[11])) + ((e_[12]+e_[13])+(e_[14]+e_[15])); \
    if (ibf_ == jb_) { \
        _Pragma("unroll") \
        for (int r_ = 0; r_ < 16; ++r_) \
            if (((r_ & 3) + 8 * (r_ >> 2) + 4 * hi) == l31) diagy[ibf_ + l31] = ACC[r_]; \
    } \
    rs[IFR] += s_; }

    for (int js = 0; js < 4; ++js) {
        asm volatile("s_waitcnt vmcnt(0)" ::: "memory");  // stage loads (1 step old) landed
        __builtin_amdgcn_s_barrier();                     // the ONLY barrier per step

        const char*          bufp  = lds + (js & 1) * 32768;
        char*                nbuf  = lds + ((js + 1) & 1) * 32768;
        const unsigned char* nsrc  = Bbase + (size_t)(js + 1) * 32768;
        const int            jbase = j0 + js * 128;

        v8i g0[4], g1[4];
        f32x16 a00, a10, a01, a11;   // a{ifrag}{jfrag}

        // ---- half-step A: j-frags 0,1 ----
        READB(g0, 0);
        STG4(0);
        READB(g1, 1);
        ZA16(a00); ZA16(a10); ZA16(a01); ZA16(a11);
        __builtin_amdgcn_s_setprio(1);
        MMJ(g0, a00, a10); MMJ(g1, a01, a11);   // 16 contiguous MFMA, 4 indep chains
        __builtin_amdgcn_s_setprio(0);
        EPJ(a00, 0, 0); EPJ(a10, 1, 0); EPJ(a01, 0, 1); EPJ(a11, 1, 1);

        // ---- half-step B: j-frags 2,3 ----
        READB(g0, 2);
        STG4(4);
        READB(g1, 3);
        ZA16(a00); ZA16(a10); ZA16(a01); ZA16(a11);
        __builtin_amdgcn_s_setprio(1);
        MMJ(g0, a00, a10); MMJ(g1, a01, a11);
        __builtin_amdgcn_s_setprio(0);
        EPJ(a00, 0, 2); EPJ(a10, 1, 2); EPJ(a01, 0, 3); EPJ(a11, 1, 3);
    }

#undef STG4
#undef READB
#undef MMJ
#undef ZA16
#undef EPJ

    // rs[ifr]: lanes l and l^32 hold the same i (col=lane&31) -> one xor-reduce
    #pragma unroll
    for (int f = 0; f < 2; ++f) {
        float v = rs[f];
        v += __shfl_xor(v, 32);
        if (lane < 32)
            rowsum_part[(size_t)(i0 + w * 64 + f * 32 + lane) * 16 + jc] = v;
    }
}

// ---------------- kernel 3: per-row finish + fused final reduce ----------------
// 8 blocks; each writes accum[bid]; the LAST finishing block (device-scope
// counter) sums the 8 partials and writes the loss.
__global__ __launch_bounds__(1024) void reduce_partial(const float* __restrict__ rowsum_part,
                                                       const float* __restrict__ diagy,
                                                       float* __restrict__ accum,
                                                       unsigned int* __restrict__ counter,
                                                       float* __restrict__ out)
{
    const int i = blockIdx.x * 1024 + threadIdx.x;
    const f32x4* p = (const f32x4*)(rowsum_part + (size_t)i * 16);
    float s = 0.f;
    #pragma unroll
    for (int k = 0; k < 4; ++k) {
        const f32x4 v = p[k];
        s += (v[0] + v[1]) + (v[2] + v[3]);
    }
    float val = __log2f(s) - diagy[i];
    #pragma unroll
    for (int d = 1; d < 64; d <<= 1) val += __shfl_xor(val, d);
    __shared__ float red[16];
    if ((threadIdx.x & 63) == 0) red[threadIdx.x >> 6] = val;
    __syncthreads();
    if (threadIdx.x == 0) {
        float t = 0.f;
        #pragma unroll
        for (int k = 0; k < 16; ++k) t += red[k];
        accum[blockIdx.x] = t;
        __threadfence();                              // publish before signaling
        const unsigned n = atomicAdd(counter, 1u);    // device-scope
        if (n == 7u) {                                // last block finalizes
            float tt = 0.f;
            const volatile float* av = (const volatile float*)accum;
            #pragma unroll
            for (int k = 0; k < 8; ++k) tt += av[k];
            out[0] = LN2 * tt * (1.0f / 8192.0f);
        }
    }
}

// ---------------- launch ----------------
extern "C" void kernel_launch(void* const* d_in, const int* in_sizes, int n_in,
                              void* d_out, int out_size, void* d_ws, size_t ws_size,
                              hipStream_t stream) {
    const float* pred = (const float*)d_in[0];
    const float* gt   = (const float*)d_in[1];
    float* out = (float*)d_out;

    char* ws = (char*)d_ws;
    float*         accum       = (float*)(ws);              // 8 f32 (fully written)
    unsigned int*  counter     = (unsigned int*)(ws + 0x100); // zeroed by convert each call
    float*         diagy       = (float*)(ws + 0x1000);     // 8192 f32 (fully overwritten)
    float*         rowsum_part = (float*)(ws + 0x10000);    // 8192 x 16 f32 = 512KB
    unsigned char* Ab          = (unsigned char*)(ws + 0x100000); // 8192x256 fp8 = 2MB
    unsigned char* Bb          = (unsigned char*)(ws + 0x300000); // 2MB

    convert_perm<<<1024, 256, 0, stream>>>(pred, gt, Ab, Bb, counter);
    gemm_lse<<<512, 256, 0, stream>>>(Ab, Bb, rowsum_part, diagy);
    reduce_partial<<<8, 1024, 0, stream>>>(rowsum_part, diagy, accum, counter, out);
}

// Round 13
// 39.160 us; speedup vs baseline: 7.3121x; 7.3121x over previous
//
#include <hip/hip_runtime.h>
#include <hip/hip_bf16.h>
#include <stdint.h>

typedef int   i32x4  __attribute__((ext_vector_type(4)));
typedef int   v8i    __attribute__((ext_vector_type(8)));
typedef float f32x4  __attribute__((ext_vector_type(4)));
typedef float f32x16 __attribute__((ext_vector_type(16)));

#define LOG2E   1.4426950408889634f
#define LN2     0.6931471805599453f
#define C_SCALED 86.56170245f   // 60*log2(e); carried in MFMA C-operand, cancels in final
#define SCALE1  0x7F7F7F7F      // e8m0 1.0 -> unit MX scales

__device__ __forceinline__ void gload_lds16(const void* gsrc, void* ldst) {
    __builtin_amdgcn_global_load_lds(
        (const __attribute__((address_space(1))) unsigned int*)gsrc,
        (__attribute__((address_space(3))) unsigned int*)ldst,
        16, 0, 0);
}

// ---------------- kernel 1: permute + fp32 -> fp8 e4m3 ----------------
// pred[b][n][c][h][w] -> A[m][c] fp8 row-major, scaled by log2(e). gt -> B[m][c] fp8.
// Also zeroes the reduce done-counter (graph-replay-safe: runs first every call).
__global__ void convert_perm(const float* __restrict__ pred, const float* __restrict__ gt,
                             unsigned char* __restrict__ Ab, unsigned char* __restrict__ Bb,
                             unsigned int* __restrict__ counter)
{
    if (blockIdx.x == 0 && threadIdx.x == 0) *counter = 0u;
    const int slab = blockIdx.x & 511;
    const bool isA = blockIdx.x < 512;
    const float scale = isA ? LOG2E : 1.0f;
    const float* src = (isA ? pred : gt) + (size_t)slab * 4096;   // [256 c][16 hw]
    unsigned char* dst = (isA ? Ab : Bb) + (size_t)slab * 4096;   // [16 hw][256 c]
    const int t  = threadIdx.x;
    const int hw = t >> 4;
    const int c0 = (t & 15) * 16;
    int d[4];
    #pragma unroll
    for (int q = 0; q < 4; ++q) {
        const float v0 = src[(c0 + q * 4 + 0) * 16 + hw] * scale;
        const float v1 = src[(c0 + q * 4 + 1) * 16 + hw] * scale;
        const float v2 = src[(c0 + q * 4 + 2) * 16 + hw] * scale;
        const float v3 = src[(c0 + q * 4 + 3) * 16 + hw] * scale;
        int r = __builtin_amdgcn_cvt_pk_fp8_f32(v0, v1, 0, false);
        r     = __builtin_amdgcn_cvt_pk_fp8_f32(v2, v3, r, true);
        d[q] = r;
    }
    *(i32x4*)(dst + hw * 256 + c0) = (i32x4){d[0], d[1], d[2], d[3]};
}

// ---------------- kernel 2: fused MX-fp8 GEMM + exp2-sum + diag ----------------
// R11 structure VERBATIM (best verified: gemm ~21us, no spill). 4-wave blocks
// (256 thr), tile 256i x 512j, A in regs (pfr 2x4 v8i = 64), B dbuf in LDS
// (2x16KB) -> 2 blocks/CU. 8 steps of 64j: 1 vmcnt(0)+barrier per step,
// 1-step-ahead stage. Register law (R7/R12 lessons): at most 2 f32x16 accs
// + 1 v8i frag-set live at any point.
__global__ __launch_bounds__(256) __attribute__((amdgpu_waves_per_eu(2, 2)))
void gemm_lse(const unsigned char* __restrict__ Ab, const unsigned char* __restrict__ Bb,
              float* __restrict__ rowsum_part, float* __restrict__ diagy)
{
    __shared__ __align__(16) char lds[32768];   // two 16KB B buffers
    const int tid  = threadIdx.x;
    const int lane = tid & 63;
    const int w    = tid >> 6;       // 0..3 (i split: 64 rows each)
    const int l31  = lane & 31;
    const int hi   = lane >> 5;

    const int jc = blockIdx.x & 15;  // same-jc blocks 16 apart -> same XCD (L2-local B)
    const int ib = blockIdx.x >> 4;  // 32 i-blocks of 256
    const int i0 = ib << 8;
    const int j0 = jc << 9;

    // ---- A fragments: 64 i-rows/wave -> 2 ifrag x 4 ks, v8i (32B = K 64) each ----
    v8i pfr[2][4];
    {
        const unsigned char* base = Ab + (size_t)(i0 + w * 64 + l31) * 256 + hi * 32;
        #pragma unroll
        for (int f = 0; f < 2; ++f)
            #pragma unroll
            for (int ks = 0; ks < 4; ++ks)
                pfr[f][ks] = *(const v8i*)(base + f * 32 * 256 + ks * 64);
    }

    const unsigned char* Bbase = Bb + (size_t)j0 * 256;
    const int ibase = i0 + w * 64;

    // stage one 64j x 256k fp8 chunk (16KB): 4 x 16B per thread, inverse-swizzled src
#define STG_ALL(NSRC, NBUF) { \
    _Pragma("unroll") \
    for (int it_ = 0; it_ < 4; ++it_) { \
        const int ob_ = it_ * 4096 + tid * 16; \
        const int sb_ = ob_ ^ (((ob_ >> 8) & 15) << 4); \
        gload_lds16((NSRC) + sb_, (NBUF) + ob_); \
    } }

    // prologue: stage step 0 into buffer 0
    STG_ALL(Bbase, lds);

    float rs[2] = {0.f, 0.f};

// read B j-frag JF (4 ks x v8i) with XOR-swizzled addresses (two b128 per v8i)
#define READB(G, JF) { \
    const char* rp_ = lds + (js & 1) * 16384 + ((JF) * 32 + l31) * 256; \
    const int sx_ = (((JF) * 32 + l31) & 15) << 4; \
    _Pragma("unroll") \
    for (int ks_ = 0; ks_ < 4; ++ks_) { \
        const int ko_ = ks_ * 64 + hi * 32; \
        const i32x4 lo_ = *(const i32x4*)(rp_ + ((ko_     ) ^ sx_)); \
        const i32x4 h_  = *(const i32x4*)(rp_ + ((ko_ + 16) ^ sx_)); \
        G[ks_] = (v8i){lo_[0], lo_[1], lo_[2], lo_[3], h_[0], h_[1], h_[2], h_[3]}; \
    } }

// 8-MFMA cluster: j-frag G x both i-frags, K=256 via 4 chained ks
#define MMJ(G, A0, A1) { \
    __builtin_amdgcn_s_setprio(1); \
    _Pragma("unroll") \
    for (int ks_ = 0; ks_ < 4; ++ks_) { \
        A0 = __builtin_amdgcn_mfma_scale_f32_32x32x64_f8f6f4( \
            G[ks_], pfr[0][ks_], A0, 0, 0, 0, SCALE1, 0, SCALE1); \
        A1 = __builtin_amdgcn_mfma_scale_f32_32x32x64_f8f6f4( \
            G[ks_], pfr[1][ks_], A1, 0, 0, 0, SCALE1, 0, SCALE1); \
    } \
    __builtin_amdgcn_s_setprio(0); }

#define ZA16(X) { _Pragma("unroll") for (int r_ = 0; r_ < 16; ++r_) X[r_] = -C_SCALED; }

// epilogue for one 32x32 tile: 16 exp2 (tree sum) + diagonal capture.
// C/D layout: col(i)=lane&31, row(j)=(r&3)+8*(r>>2)+4*(lane>>5)
#define EPJ(ACC, IFR, JF) { \
    const int jb_  = jbase + (JF) * 32; \
    const int ibf_ = ibase + (IFR) * 32; \
    float e_[16]; \
    _Pragma("unroll") for (int r_ = 0; r_ < 16; ++r_) e_[r_] = __builtin_amdgcn_exp2f(ACC[r_]); \
    float s_ = ((e_[0]+e_[1])+(e_[2]+e_[3])) + ((e_[4]+e_[5])+(e_[6]+e_[7])) \
             + ((e_[8]+e_[9])+(e_[10]+e_[11])) + ((e_[12]+e_[13])+(e_[14]+e_[15])); \
    if (ibf_ == jb_) { \
        _Pragma("unroll") \
        for (int r_ = 0; r_ < 16; ++r_) \
            if (((r_ & 3) + 8 * (r_ >> 2) + 4 * hi) == l31) diagy[ibf_ + l31] = ACC[r_]; \
    } \
    rs[IFR] += s_; }

    for (int js = 0; js < 8; ++js) {
        asm volatile("s_waitcnt vmcnt(0)" ::: "memory");  // stage loads (1 step old) landed
        __builtin_amdgcn_s_barrier();                     // the ONLY barrier per step

        char*                nbuf  = lds + ((js + 1) & 1) * 16384;
        const unsigned char* nsrc  = Bbase + (size_t)(js + 1) * 16384;
        const int            jbase = j0 + js * 64;

        v8i g0[4], g1[4];
        f32x16 a00, a10, a01, a11;   // a{ifrag}{jfrag}; only one pair live at a time

        READB(g0, 0);
        if (js < 7) STG_ALL(nsrc, nbuf);
        READB(g1, 1);

        ZA16(a00); ZA16(a10);
        MMJ(g0, a00, a10);
        EPJ(a00, 0, 0); EPJ(a10, 1, 0);    // EP overlaps SIMD-mate's MFMA

        ZA16(a01); ZA16(a11);
        MMJ(g1, a01, a11);
        EPJ(a01, 0, 1); EPJ(a11, 1, 1);
    }

#undef STG_ALL
#undef READB
#undef MMJ
#undef ZA16
#undef EPJ

    // rs[ifr]: lanes l and l^32 hold the same i (col=lane&31) -> one xor-reduce
    #pragma unroll
    for (int f = 0; f < 2; ++f) {
        float v = rs[f];
        v += __shfl_xor(v, 32);
        if (lane < 32)
            rowsum_part[(size_t)(i0 + w * 64 + f * 32 + lane) * 16 + jc] = v;
    }
}

// ---------------- kernel 3: per-row finish + fused final reduce ----------------
// 8 blocks; each writes accum[bid]; the LAST finishing block (device-scope
// counter, zeroed by convert_perm this call) sums the partials -> out.
__global__ __launch_bounds__(1024) void reduce_partial(const float* __restrict__ rowsum_part,
                                                       const float* __restrict__ diagy,
                                                       float* __restrict__ accum,
                                                       unsigned int* __restrict__ counter,
                                                       float* __restrict__ out)
{
    const int i = blockIdx.x * 1024 + threadIdx.x;
    const f32x4* p = (const f32x4*)(rowsum_part + (size_t)i * 16);
    float s = 0.f;
    #pragma unroll
    for (int k = 0; k < 4; ++k) {
        const f32x4 v = p[k];
        s += (v[0] + v[1]) + (v[2] + v[3]);
    }
    float val = __log2f(s) - diagy[i];
    #pragma unroll
    for (int d = 1; d < 64; d <<= 1) val += __shfl_xor(val, d);
    __shared__ float red[16];
    if ((threadIdx.x & 63) == 0) red[threadIdx.x >> 6] = val;
    __syncthreads();
    if (threadIdx.x == 0) {
        float t = 0.f;
        #pragma unroll
        for (int k = 0; k < 16; ++k) t += red[k];
        accum[blockIdx.x] = t;
        __threadfence();                              // publish before signaling
        const unsigned n = atomicAdd(counter, 1u);    // device-scope
        if (n == 7u) {                                // last block finalizes
            float tt = 0.f;
            const volatile float* av = (const volatile float*)accum;
            #pragma unroll
            for (int k = 0; k < 8; ++k) tt += av[k];
            out[0] = LN2 * tt * (1.0f / 8192.0f);
        }
    }
}

// ---------------- launch ----------------
extern "C" void kernel_launch(void* const* d_in, const int* in_sizes, int n_in,
                              void* d_out, int out_size, void* d_ws, size_t ws_size,
                              hipStream_t stream) {
    const float* pred = (const float*)d_in[0];
    const float* gt   = (const float*)d_in[1];
    float* out = (float*)d_out;

    char* ws = (char*)d_ws;
    float*         accum       = (float*)(ws);                // 8 f32 (fully written)
    unsigned int*  counter     = (unsigned int*)(ws + 0x100); // zeroed by convert each call
    float*         diagy       = (float*)(ws + 0x1000);       // 8192 f32 (fully overwritten)
    float*         rowsum_part = (float*)(ws + 0x10000);      // 8192 x 16 f32 = 512KB
    unsigned char* Ab          = (unsigned char*)(ws + 0x100000); // 8192x256 fp8 = 2MB
    unsigned char* Bb          = (unsigned char*)(ws + 0x300000); // 2MB

    convert_perm<<<1024, 256, 0, stream>>>(pred, gt, Ab, Bb, counter);
    gemm_lse<<<512, 256, 0, stream>>>(Ab, Bb, rowsum_part, diagy);
    reduce_partial<<<8, 1024, 0, stream>>>(rowsum_part, diagy, accum, counter, out);
}